// Round 8
// baseline (282.767 us; speedup 1.0000x reference)
//
#include <hip/hip_runtime.h>

typedef unsigned short u16;
typedef unsigned int   u32;
typedef __attribute__((ext_vector_type(8))) short short8;   // 8 x bf16 (4 VGPRs)
typedef __attribute__((ext_vector_type(4))) float f32x4;

#define MFMA16(a, b, c) __builtin_amdgcn_mfma_f32_16x16x32_bf16(a, b, c, 0, 0, 0)

constexpr int Lv = 2048, Hv = 8, Ev = 64, HE = Hv * Ev; // HE=512
constexpr float QSCALE = 0.18033688011112042f;          // 0.125 * log2(e)

__device__ __forceinline__ float bf2f(u16 u) {
    u32 x = ((u32)u) << 16;
    return __builtin_bit_cast(float, x);
}
__device__ __forceinline__ u16 f2bf(float f) {   // RNE, finite inputs
    u32 x = __builtin_bit_cast(u32, f);
    u32 r = ((x >> 16) & 1u) + 0x7fffu;
    return (u16)((x + r) >> 16);
}
__device__ __forceinline__ u32 pkbf(float a, float b) {
#if __has_builtin(__builtin_amdgcn_cvt_pk_bf16_f32)
    typedef __attribute__((ext_vector_type(2))) __bf16 bf16x2;
    bf16x2 v = __builtin_amdgcn_cvt_pk_bf16_f32(a, b);
    return __builtin_bit_cast(u32, v);
#else
    return (u32)f2bf(a) | ((u32)f2bf(b) << 16);
#endif
}
__device__ __forceinline__ float fexp2(float x) {
#if __has_builtin(__builtin_amdgcn_exp2f)
    return __builtin_amdgcn_exp2f(x);
#else
    return exp2f(x);
#endif
}

// Runtime dtype sniff (validated rounds 2-7: fp32 inputs detected correctly).
__device__ __forceinline__ int detect_isbf16(const u32* q32, int lane) {
    u32 w0 = q32[2 * lane];
    u32 w1 = q32[2 * lane + 1];
    u16 uu[4] = { (u16)(w0 & 0xffff), (u16)(w0 >> 16),
                  (u16)(w1 & 0xffff), (u16)(w1 >> 16) };
    int p = 0, z = 0;
#pragma unroll
    for (int j = 0; j < 4; ++j) {
        u16 mgn = (u16)(uu[j] & 0x7fff);
        int ex  = mgn >> 7;
        bool zero = (mgn == 0);
        bool pl   = zero || (ex >= 115 && ex <= 132);
        p += pl ? 1 : 0;
        if ((j & 1) == 0) z += zero ? 1 : 0;
    }
    int acc = p | (z << 16);
#pragma unroll
    for (int o = 1; o < 64; o <<= 1) acc += __shfl_xor(acc, o);
    int ps = acc & 0xffff, zs = acc >> 16;
    if (zs >= 100) return 0;
    return (ps >= 240) ? 1 : 0;
}

__device__ __forceinline__ short8 cvt8s(const float* p, float s) {
    float4 a = *(const float4*)p, b4 = *(const float4*)(p + 4);
    u32 r[4] = { pkbf(a.x * s, a.y * s), pkbf(a.z * s, a.w * s),
                 pkbf(b4.x * s, b4.y * s), pkbf(b4.z * s, b4.w * s) };
    return *(short8*)r;
}

// ---------------------------------------------------------------------------
// Fused full attention + l=0 local blend.
// grid = 512 (16 row-blocks x 32 bh), block = 512 (8 waves).
// Parity split-K + MQ=2: query group g = w&3 owns rows [row0+g*32, +32);
// waves 0-3 process even key-tiles, waves 4-7 the same rows on odd tiles.
// Each K/V LDS fragment read feeds TWO MFMAs; O/Ssum combined additively
// at the end (exact: fixed-offset exp2 softmax, no online rescale).
// K/V double-buffered LDS + register prefetch; one barrier per iteration.
// ---------------------------------------------------------------------------
template <int ISBF>
__device__ __forceinline__ void attn_impl(
    const void* __restrict__ qv, const void* __restrict__ kv,
    const void* __restrict__ vv, const void* __restrict__ alphav,
    void* __restrict__ outv, u16* Klds, u16* Vt, u16* PldsAll, float* Scmb)
{
    const int tid  = threadIdx.x;          // 0..511
    const int w    = tid >> 6;             // 0..7
    const int g    = w & 3;                // query group
    const int par  = w >> 2;               // key parity (wave-uniform)
    const int lane = tid & 63;
    const int quad = lane >> 4;
    const int m    = lane & 15;

    // XCD-aware mapping: xcd = fid&7 handles bh in {4*xcd .. 4*xcd+3}.
    const int fid = blockIdx.x;
    const int bh  = (fid & 7) * 4 + ((fid >> 3) & 3);
    const int rb  = fid >> 5;
    const int b   = bh >> 3, h = bh & 7;
    const int row0 = rb * 128;

    const size_t bhoff = (size_t)b * Lv * HE + h * Ev;
    const u16*   q16 = (const u16*)qv + bhoff;
    const u16*   k16 = (const u16*)kv + bhoff;
    const u16*   v16 = (const u16*)vv + bhoff;
    const float* q32 = (const float*)qv + bhoff;
    const float* k32 = (const float*)kv + bhoff;
    const float* v32 = (const float*)vv + bhoff;

    // Q fragments (pre-scaled). B-operand of the S^T MFMA:
    // B[col=query=m][k=32c+8*quad+j].
    short8 qf[2][2];
#pragma unroll
    for (int mt = 0; mt < 2; ++mt) {
        size_t ro = (size_t)(row0 + g * 32 + mt * 16 + m) * HE + quad * 8;
        if (ISBF) {
            short8 t0 = *(const short8*)(q16 + ro);
            short8 t1 = *(const short8*)(q16 + ro + 32);
#pragma unroll
            for (int j = 0; j < 8; ++j) {
                qf[mt][0][j] = (short)f2bf(bf2f((u16)t0[j]) * QSCALE);
                qf[mt][1][j] = (short)f2bf(bf2f((u16)t1[j]) * QSCALE);
            }
        } else {
            qf[mt][0] = cvt8s(q32 + ro, QSCALE);
            qf[mt][1] = cvt8s(q32 + ro + 32, QSCALE);
        }
    }

    short8 ones8;
#pragma unroll
    for (int j = 0; j < 8; ++j) ones8[j] = (short)0x3F80;   // bf16 1.0

    f32x4 O[2][4];
    f32x4 Ssum[2];
#pragma unroll
    for (int mt = 0; mt < 2; ++mt) {
        Ssum[mt] = f32x4{0.f, 0.f, 0.f, 0.f};
#pragma unroll
        for (int et = 0; et < 4; ++et) O[mt][et] = f32x4{0.f, 0.f, 0.f, 0.f};
    }

    // K staging (round-5 pattern): thread owns chunk tid: key=tid>>3,
    // slot=tid&7; XOR swizzle folded into GLOBAL read offset.
    const int kkey = tid >> 3, ksl = tid & 7;
    const int koff = kkey * HE + (ksl ^ (kkey & 7)) * 8;
    // V staging: thread owns key-pair (2*pp, 2*pp+1), e-quad eq.
    const int eq = tid & 15, pp = tid >> 4;
    const int kcv = pp >> 2, pq = pp & 3;

    u16* Pw = PldsAll + w * 2048;   // 32 q-rows x 64 keys per wave

    // ---- prefetch registers ----
    uint4 kru; uint2 vru0, vru1;        // bf16 path
    float4 kfa, kfb, vfa, vfb;          // fp32 path

    auto load_tile = [&](int KT) {
        if (ISBF) {
            kru  = *(const uint4*)(k16 + (size_t)KT * 64 * HE + koff);
            const u16* vp = v16 + (size_t)(KT * 64 + 2 * pp) * HE + eq * 4;
            vru0 = *(const uint2*)vp;
            vru1 = *(const uint2*)(vp + HE);
        } else {
            const float* kp = k32 + (size_t)KT * 64 * HE + koff;
            kfa = *(const float4*)kp;
            kfb = *(const float4*)(kp + 4);
            const float* vp = v32 + (size_t)(KT * 64 + 2 * pp) * HE + eq * 4;
            vfa = *(const float4*)vp;
            vfb = *(const float4*)(vp + HE);
        }
    };
    auto store_tile = [&](u16* KB, u16* VB) {
        if (ISBF) {
            *(uint4*)&KB[tid * 8] = kru;
            const u16* a0 = (const u16*)&vru0;
            const u16* a1 = (const u16*)&vru1;
#pragma unroll
            for (int j = 0; j < 4; ++j) {
                int e  = eq * 4 + j;
                int sl = kcv ^ ((e + (e >> 3)) & 7);
                u32 val = (u32)a0[j] | ((u32)a1[j] << 16);
                *(u32*)&VB[e * 64 + sl * 8 + pq * 2] = val;
            }
        } else {
            u32 kk[4] = { pkbf(kfa.x, kfa.y), pkbf(kfa.z, kfa.w),
                          pkbf(kfb.x, kfb.y), pkbf(kfb.z, kfb.w) };
            *(uint4*)&KB[tid * 8] = *(uint4*)kk;
            float t0[4], t1[4];
            *(float4*)t0 = vfa; *(float4*)t1 = vfb;
#pragma unroll
            for (int j = 0; j < 4; ++j) {
                int e  = eq * 4 + j;
                int sl = kcv ^ ((e + (e >> 3)) & 7);
                *(u32*)&VB[e * 64 + sl * 8 + pq * 2] = pkbf(t0[j], t1[j]);
            }
        }
    };

    // ---- prologue: stage tile 0 into buffer 0 ----
    load_tile(0);
    store_tile(Klds, Vt);
    __syncthreads();

    for (int kt = 0; kt < 32; ++kt) {
        u16* Kb = Klds + (kt & 1) * 4096;
        u16* Vb = Vt   + (kt & 1) * 4096;
        u16* Kn = Klds + ((kt & 1) ^ 1) * 4096;
        u16* Vn = Vt   + ((kt & 1) ^ 1) * 4096;

        if (kt < 31) load_tile(kt + 1);   // in flight across compute below

        if ((kt & 1) == par) {            // wave-uniform guard
            // ---- S^T = K (Q*c)^T : St[mt][nt] key=nt*16+quad*4+r, query=m ----
            f32x4 St[2][4];
#pragma unroll
            for (int mt = 0; mt < 2; ++mt)
#pragma unroll
                for (int nt = 0; nt < 4; ++nt) St[mt][nt] = f32x4{0.f,0.f,0.f,0.f};
#pragma unroll
            for (int c = 0; c < 2; ++c) {
#pragma unroll
                for (int nt = 0; nt < 4; ++nt) {
                    int krow = nt * 16 + m;
                    int sl   = (4 * c + quad) ^ (m & 7);
                    short8 kfr = *(const short8*)&Kb[krow * 64 + sl * 8];
                    St[0][nt] = MFMA16(kfr, qf[0][c], St[0][nt]);  // 1 read,
                    St[1][nt] = MFMA16(kfr, qf[1][c], St[1][nt]);  // 2 MFMAs
                }
            }

            // ---- P = exp2(St): one b64 store per (mt,nt) ----
#pragma unroll
            for (int mt = 0; mt < 2; ++mt) {
#pragma unroll
                for (int nt = 0; nt < 4; ++nt) {
                    u32 u0 = pkbf(fexp2(St[mt][nt][0]), fexp2(St[mt][nt][1]));
                    u32 u1 = pkbf(fexp2(St[mt][nt][2]), fexp2(St[mt][nt][3]));
                    int G   = 2 * nt + (quad >> 1);
                    int off = (mt * 16 + m) * 64 + ((G ^ (m & 7)) * 8) + (quad & 1) * 4;
                    uint2 val; val.x = u0; val.y = u1;
                    *(uint2*)&Pw[off] = val;   // per-wave buffer, no barrier
                }
            }

            // ---- O += P V;  Ssum += P * ones; V fragment shared by both mt ----
#pragma unroll
            for (int c = 0; c < 2; ++c) {
                int Gp = (4 * c + quad) ^ (m & 7);
                short8 pf0 = *(const short8*)&Pw[m * 64 + Gp * 8];
                short8 pf1 = *(const short8*)&Pw[(16 + m) * 64 + Gp * 8];
                Ssum[0] = MFMA16(pf0, ones8, Ssum[0]);
                Ssum[1] = MFMA16(pf1, ones8, Ssum[1]);
#pragma unroll
                for (int et = 0; et < 4; ++et) {
                    int e  = et * 16 + m;
                    int sl = (4 * c + quad) ^ ((e + (e >> 3)) & 7);
                    short8 vfr = *(const short8*)&Vb[e * 64 + sl * 8];
                    O[0][et] = MFMA16(pf0, vfr, O[0][et]);   // 1 read, 2 MFMAs
                    O[1][et] = MFMA16(pf1, vfr, O[1][et]);
                }
            }
        }

        if (kt < 31) {
            store_tile(Kn, Vn);   // buffer last read in iter kt-1; safe
            __syncthreads();
        }
    }

    // ---- combine: upper waves deposit O/Ssum, lower waves add ----
    __syncthreads();                      // all compute done; P space free
    if (w >= 4) {
        float* ob = (float*)PldsAll + (size_t)(w - 4) * 2048;  // 32 x 64 f32
        float* sb = Scmb + (w - 4) * 512;                      // 8 x 64 f32
#pragma unroll
        for (int mt = 0; mt < 2; ++mt) {
#pragma unroll
            for (int et = 0; et < 4; ++et)
#pragma unroll
                for (int r = 0; r < 4; ++r)
                    ob[(mt * 16 + et * 4 + r) * 64 + lane] = O[mt][et][r];
#pragma unroll
            for (int r = 0; r < 4; ++r)
                sb[(mt * 4 + r) * 64 + lane] = Ssum[mt][r];
        }
    }
    __syncthreads();

    // ---- l=0 local attention (wave 0), kept in registers ----
    float locv[4] = {0.f, 0.f, 0.f, 0.f};
    float wgt = 0.f;
    const bool isrow0 = (rb == 0) && (w == 0) && (quad == 0);
    if (rb == 0 && w == 0) {
        const int e = lane;
        const size_t base = bhoff + e;
#define LDIN(p, i) (ISBF ? bf2f(((const u16*)(p))[i]) : ((const float*)(p))[i])
        float qe = LDIN(qv, base);
        float s[9];
#pragma unroll
        for (int j = 0; j < 9; ++j) {
            float prod = qe * LDIN(kv, base + (size_t)j * HE);
#pragma unroll
            for (int o = 1; o < 64; o <<= 1) prod += __shfl_xor(prod, o);
            s[j] = prod * 0.125f;
        }
        float mx = s[0];
#pragma unroll
        for (int j = 1; j < 9; ++j) mx = fmaxf(mx, s[j]);
        float we[9];
#pragma unroll
        for (int j = 0; j < 9; ++j) we[j] = expf(s[j] - mx);
        float denom = 9.f * we[0];
        float acc   = 9.f * we[0] * LDIN(vv, base);
#pragma unroll
        for (int j = 1; j < 9; ++j) {
            denom += we[j];
            acc   += we[j] * LDIN(vv, base + (size_t)j * HE);
        }
        float loc = acc / denom;

        float a;
        if (ISBF) {
            a = bf2f(((const u16*)alphav)[0]);
            if (!(a >= 0.0f && a <= 1.0f)) {
                float af = ((const float*)alphav)[0];
                if (af >= 0.0f && af <= 1.0f) a = af;
            }
        } else {
            a = ((const float*)alphav)[0];
            if (!(a >= 0.0f && a <= 1.0f)) {
                float ab = bf2f(((const u16*)alphav)[0]);
                if (ab >= 0.0f && ab <= 1.0f) a = ab;
            }
        }
        wgt = 1.f / (1.f + expf(-a));
#pragma unroll
        for (int et = 0; et < 4; ++et) locv[et] = __shfl(loc, et * 16 + m);
#undef LDIN
    }

    // ---- lower waves: merge partner partials, normalize, blend, store ----
    if (w < 4) {
        const float* ob = (const float*)PldsAll + (size_t)w * 2048;
        const float* sb = Scmb + w * 512;
#pragma unroll
        for (int mt = 0; mt < 2; ++mt) {
#pragma unroll
            for (int r = 0; r < 4; ++r)
                Ssum[mt][r] += sb[(mt * 4 + r) * 64 + lane];
#pragma unroll
            for (int et = 0; et < 4; ++et)
#pragma unroll
                for (int r = 0; r < 4; ++r)
                    O[mt][et][r] += ob[(mt * 16 + et * 4 + r) * 64 + lane];
        }
#pragma unroll
        for (int mt = 0; mt < 2; ++mt) {
#pragma unroll
            for (int r = 0; r < 4; ++r) {
                float inv = 1.0f / Ssum[mt][r];
                int row = row0 + g * 32 + mt * 16 + quad * 4 + r;
                size_t oo = (size_t)(b * Lv + row) * HE + h * Ev + m;
                bool blend = isrow0 && (mt == 0) && (r == 0);
#pragma unroll
                for (int et = 0; et < 4; ++et) {
                    float res = O[mt][et][r] * inv;
                    if (blend) res = wgt * res + (1.f - wgt) * locv[et];
                    if (ISBF) ((u16*)outv)[oo + et * 16] = f2bf(res);
                    else      ((float*)outv)[oo + et * 16] = res;
                }
            }
        }
    }
}

__global__ __launch_bounds__(512, 4) void attn_kernel(
    const void* __restrict__ qv, const void* __restrict__ kv,
    const void* __restrict__ vv, const void* __restrict__ alphav,
    void* __restrict__ outv)
{
    __shared__ u16 Klds[2 * 4096];      // double-buffered [key][e], swizzled
    __shared__ u16 Vt[2 * 4096];        // double-buffered [e][key], swizzled
    __shared__ u16 Plds[8 * 2048];      // per-wave P / combine O (reused)
    __shared__ float Scmb[4 * 512];     // Ssum combine

    const int isbf = detect_isbf16((const u32*)qv, threadIdx.x & 63);
    if (isbf) attn_impl<1>(qv, kv, vv, alphav, outv, Klds, Vt, Plds, Scmb);
    else      attn_impl<0>(qv, kv, vv, alphav, outv, Klds, Vt, Plds, Scmb);
}

extern "C" void kernel_launch(void* const* d_in, const int* in_sizes, int n_in,
                              void* d_out, int out_size, void* d_ws, size_t ws_size,
                              hipStream_t stream) {
    hipLaunchKernelGGL(attn_kernel, dim3(512), dim3(512), 0, stream,
                       d_in[0], d_in[1], d_in[2], d_in[3], d_out);
}

// Round 9
// 152.637 us; speedup vs baseline: 1.8526x; 1.8526x over previous
//
#include <hip/hip_runtime.h>

typedef unsigned short u16;
typedef unsigned int   u32;
typedef __attribute__((ext_vector_type(8))) short short8;   // 8 x bf16 (4 VGPRs)
typedef __attribute__((ext_vector_type(4))) float f32x4;

#define MFMA16(a, b, c) __builtin_amdgcn_mfma_f32_16x16x32_bf16(a, b, c, 0, 0, 0)

constexpr int Lv = 2048, Hv = 8, Ev = 64, HE = Hv * Ev; // HE=512
constexpr float QSCALE = 0.18033688011112042f;          // 0.125 * log2(e)

__device__ __forceinline__ float bf2f(u16 u) {
    u32 x = ((u32)u) << 16;
    return __builtin_bit_cast(float, x);
}
__device__ __forceinline__ u16 f2bf(float f) {   // RNE, finite inputs
    u32 x = __builtin_bit_cast(u32, f);
    u32 r = ((x >> 16) & 1u) + 0x7fffu;
    return (u16)((x + r) >> 16);
}
__device__ __forceinline__ u32 pkbf(float a, float b) {
#if __has_builtin(__builtin_amdgcn_cvt_pk_bf16_f32)
    typedef __attribute__((ext_vector_type(2))) __bf16 bf16x2;
    bf16x2 v = __builtin_amdgcn_cvt_pk_bf16_f32(a, b);
    return __builtin_bit_cast(u32, v);
#else
    return (u32)f2bf(a) | ((u32)f2bf(b) << 16);
#endif
}
__device__ __forceinline__ float fexp2(float x) {
#if __has_builtin(__builtin_amdgcn_exp2f)
    return __builtin_amdgcn_exp2f(x);
#else
    return exp2f(x);
#endif
}

// Runtime dtype sniff (validated rounds 2-8: fp32 inputs detected correctly).
__device__ __forceinline__ int detect_isbf16(const u32* q32, int lane) {
    u32 w0 = q32[2 * lane];
    u32 w1 = q32[2 * lane + 1];
    u16 uu[4] = { (u16)(w0 & 0xffff), (u16)(w0 >> 16),
                  (u16)(w1 & 0xffff), (u16)(w1 >> 16) };
    int p = 0, z = 0;
#pragma unroll
    for (int j = 0; j < 4; ++j) {
        u16 mgn = (u16)(uu[j] & 0x7fff);
        int ex  = mgn >> 7;
        bool zero = (mgn == 0);
        bool pl   = zero || (ex >= 115 && ex <= 132);
        p += pl ? 1 : 0;
        if ((j & 1) == 0) z += zero ? 1 : 0;
    }
    int acc = p | (z << 16);
#pragma unroll
    for (int o = 1; o < 64; o <<= 1) acc += __shfl_xor(acc, o);
    int ps = acc & 0xffff, zs = acc >> 16;
    if (zs >= 100) return 0;
    return (ps >= 240) ? 1 : 0;
}

__device__ __forceinline__ short8 cvt8s(const float* p, float s) {
    float4 a = *(const float4*)p, b4 = *(const float4*)(p + 4);
    u32 r[4] = { pkbf(a.x * s, a.y * s), pkbf(a.z * s, a.w * s),
                 pkbf(b4.x * s, b4.y * s), pkbf(b4.z * s, b4.w * s) };
    return *(short8*)r;
}

// ---------------------------------------------------------------------------
// Fused full attention + l=0 local blend.
// grid = 512 (16 row-blocks x 32 bh), block = 512 (8 waves).
// Parity split-K + MQ=2: query group g = w&3 owns rows [row0+g*32, +32);
// waves 0-3 process even key-tiles, waves 4-7 the same rows on odd tiles.
// O/Ssum combined additively at the end (exact: fixed-offset exp2 softmax).
// Register diet vs round 8 (which spilled at the 128-reg cap):
//  - nt-outer S loop: St live state 8 floats (was 32)
//  - load_tile converts to bf16 immediately: prefetch 8 regs (was 16)
//  - Scmb overlaid on dead Klds
// ---------------------------------------------------------------------------
template <int ISBF>
__device__ __forceinline__ void attn_impl(
    const void* __restrict__ qv, const void* __restrict__ kv,
    const void* __restrict__ vv, const void* __restrict__ alphav,
    void* __restrict__ outv, u16* Klds, u16* Vt, u16* PldsAll)
{
    const int tid  = threadIdx.x;          // 0..511
    const int w    = tid >> 6;             // 0..7
    const int g    = w & 3;                // query group
    const int par  = w >> 2;               // key parity (wave-uniform)
    const int lane = tid & 63;
    const int quad = lane >> 4;
    const int m    = lane & 15;

    // XCD-aware mapping: xcd = fid&7 handles bh in {4*xcd .. 4*xcd+3}.
    const int fid = blockIdx.x;
    const int bh  = (fid & 7) * 4 + ((fid >> 3) & 3);
    const int rb  = fid >> 5;
    const int b   = bh >> 3, h = bh & 7;
    const int row0 = rb * 128;

    const size_t bhoff = (size_t)b * Lv * HE + h * Ev;
    const u16*   q16 = (const u16*)qv + bhoff;
    const u16*   k16 = (const u16*)kv + bhoff;
    const u16*   v16 = (const u16*)vv + bhoff;
    const float* q32 = (const float*)qv + bhoff;
    const float* k32 = (const float*)kv + bhoff;
    const float* v32 = (const float*)vv + bhoff;

    // Q fragments (pre-scaled). B-operand of the S^T MFMA:
    // B[col=query=m][k=32c+8*quad+j].
    short8 qf[2][2];
#pragma unroll
    for (int mt = 0; mt < 2; ++mt) {
        size_t ro = (size_t)(row0 + g * 32 + mt * 16 + m) * HE + quad * 8;
        if (ISBF) {
            short8 t0 = *(const short8*)(q16 + ro);
            short8 t1 = *(const short8*)(q16 + ro + 32);
#pragma unroll
            for (int j = 0; j < 8; ++j) {
                qf[mt][0][j] = (short)f2bf(bf2f((u16)t0[j]) * QSCALE);
                qf[mt][1][j] = (short)f2bf(bf2f((u16)t1[j]) * QSCALE);
            }
        } else {
            qf[mt][0] = cvt8s(q32 + ro, QSCALE);
            qf[mt][1] = cvt8s(q32 + ro + 32, QSCALE);
        }
    }

    short8 ones8;
#pragma unroll
    for (int j = 0; j < 8; ++j) ones8[j] = (short)0x3F80;   // bf16 1.0

    f32x4 O[2][4];
    f32x4 Ssum[2];
#pragma unroll
    for (int mt = 0; mt < 2; ++mt) {
        Ssum[mt] = f32x4{0.f, 0.f, 0.f, 0.f};
#pragma unroll
        for (int et = 0; et < 4; ++et) O[mt][et] = f32x4{0.f, 0.f, 0.f, 0.f};
    }

    // K staging: thread owns chunk tid: key=tid>>3, slot=tid&7; XOR swizzle
    // folded into GLOBAL read offset, LDS write linear at tid*8.
    const int kkey = tid >> 3, ksl = tid & 7;
    const int koff = kkey * HE + (ksl ^ (kkey & 7)) * 8;
    // V staging: thread owns key-pair (2*pp, 2*pp+1), e-quad eq.
    const int eq = tid & 15, pp = tid >> 4;
    const int kcv = pp >> 2, pq = pp & 3;

    u16* Pw = PldsAll + w * 2048;   // 32 q-rows x 64 keys per wave

    // ---- prefetch registers (already bf16-packed: 8 VGPRs total) ----
    uint4 kru;   // K chunk, 8 bf16
    uint4 vpk;   // V: 4 x (key-even, key-odd) bf16 pairs

    auto load_tile = [&](int KT) {
        if (ISBF) {
            kru = *(const uint4*)(k16 + (size_t)KT * 64 * HE + koff);
            const u16* vp = v16 + (size_t)(KT * 64 + 2 * pp) * HE + eq * 4;
            uint2 r0 = *(const uint2*)vp;
            uint2 r1 = *(const uint2*)(vp + HE);
            const u16* a0 = (const u16*)&r0;
            const u16* a1 = (const u16*)&r1;
            u32 vv4[4];
#pragma unroll
            for (int j = 0; j < 4; ++j) vv4[j] = (u32)a0[j] | ((u32)a1[j] << 16);
            vpk = *(uint4*)vv4;
        } else {
            const float* kp = k32 + (size_t)KT * 64 * HE + koff;
            float4 ka = *(const float4*)kp;
            float4 kb2 = *(const float4*)(kp + 4);
            u32 kk[4] = { pkbf(ka.x, ka.y), pkbf(ka.z, ka.w),
                          pkbf(kb2.x, kb2.y), pkbf(kb2.z, kb2.w) };
            kru = *(uint4*)kk;
            const float* vp = v32 + (size_t)(KT * 64 + 2 * pp) * HE + eq * 4;
            float4 f0 = *(const float4*)vp;
            float4 f1 = *(const float4*)(vp + HE);
            u32 vv4[4] = { pkbf(f0.x, f1.x), pkbf(f0.y, f1.y),
                           pkbf(f0.z, f1.z), pkbf(f0.w, f1.w) };
            vpk = *(uint4*)vv4;
        }
    };
    auto store_tile = [&](u16* KB, u16* VB) {
        *(uint4*)&KB[tid * 8] = kru;
        const u32* vp4 = (const u32*)&vpk;
#pragma unroll
        for (int j = 0; j < 4; ++j) {
            int e  = eq * 4 + j;
            int sl = kcv ^ ((e + (e >> 3)) & 7);
            *(u32*)&VB[e * 64 + sl * 8 + pq * 2] = vp4[j];
        }
    };

    // ---- prologue: stage tile 0 into buffer 0 ----
    load_tile(0);
    store_tile(Klds, Vt);
    __syncthreads();

    for (int kt = 0; kt < 32; ++kt) {
        u16* Kb = Klds + (kt & 1) * 4096;
        u16* Vb = Vt   + (kt & 1) * 4096;
        u16* Kn = Klds + ((kt & 1) ^ 1) * 4096;
        u16* Vn = Vt   + ((kt & 1) ^ 1) * 4096;

        if (kt < 31) load_tile(kt + 1);   // in flight across compute below

        if ((kt & 1) == par) {            // wave-uniform guard
            // ---- S^T per nt: compute, exp2, stage P, release (St live = 8) ----
#pragma unroll
            for (int nt = 0; nt < 4; ++nt) {
                f32x4 St0 = f32x4{0.f, 0.f, 0.f, 0.f};
                f32x4 St1 = f32x4{0.f, 0.f, 0.f, 0.f};
#pragma unroll
                for (int c = 0; c < 2; ++c) {
                    int krow = nt * 16 + m;
                    int sl   = (4 * c + quad) ^ (m & 7);
                    short8 kfr = *(const short8*)&Kb[krow * 64 + sl * 8];
                    St0 = MFMA16(kfr, qf[0][c], St0);   // 1 read,
                    St1 = MFMA16(kfr, qf[1][c], St1);   // 2 MFMAs
                }
                int G   = 2 * nt + (quad >> 1);
                int off = m * 64 + ((G ^ (m & 7)) * 8) + (quad & 1) * 4;
                uint2 val;
                val.x = pkbf(fexp2(St0[0]), fexp2(St0[1]));
                val.y = pkbf(fexp2(St0[2]), fexp2(St0[3]));
                *(uint2*)&Pw[off] = val;
                val.x = pkbf(fexp2(St1[0]), fexp2(St1[1]));
                val.y = pkbf(fexp2(St1[2]), fexp2(St1[3]));
                *(uint2*)&Pw[off + 16 * 64] = val;
            }

            // ---- O += P V;  Ssum += P * ones; V fragment shared by both mt ----
#pragma unroll
            for (int c = 0; c < 2; ++c) {
                int Gp = (4 * c + quad) ^ (m & 7);
                short8 pf0 = *(const short8*)&Pw[m * 64 + Gp * 8];
                short8 pf1 = *(const short8*)&Pw[(16 + m) * 64 + Gp * 8];
                Ssum[0] = MFMA16(pf0, ones8, Ssum[0]);
                Ssum[1] = MFMA16(pf1, ones8, Ssum[1]);
#pragma unroll
                for (int et = 0; et < 4; ++et) {
                    int e  = et * 16 + m;
                    int sl = (4 * c + quad) ^ ((e + (e >> 3)) & 7);
                    short8 vfr = *(const short8*)&Vb[e * 64 + sl * 8];
                    O[0][et] = MFMA16(pf0, vfr, O[0][et]);   // 1 read, 2 MFMAs
                    O[1][et] = MFMA16(pf1, vfr, O[1][et]);
                }
            }
        }

        if (kt < 31) {
            store_tile(Kn, Vn);   // buffer last read in iter kt-1; safe
            __syncthreads();
        }
    }

    // ---- combine: upper waves deposit O/Ssum, lower waves add ----
    float* Scmb = (float*)Klds;           // Klds dead after the loop
    __syncthreads();                      // all compute done; P space free
    if (w >= 4) {
        float* ob = (float*)PldsAll + (size_t)(w - 4) * 2048;  // 32 x 64 f32
        float* sb = Scmb + (w - 4) * 512;                      // 8 x 64 f32
#pragma unroll
        for (int mt = 0; mt < 2; ++mt) {
#pragma unroll
            for (int et = 0; et < 4; ++et)
#pragma unroll
                for (int r = 0; r < 4; ++r)
                    ob[(mt * 16 + et * 4 + r) * 64 + lane] = O[mt][et][r];
#pragma unroll
            for (int r = 0; r < 4; ++r)
                sb[(mt * 4 + r) * 64 + lane] = Ssum[mt][r];
        }
    }
    __syncthreads();

    // ---- l=0 local attention (wave 0), kept in registers ----
    float locv[4] = {0.f, 0.f, 0.f, 0.f};
    float wgt = 0.f;
    const bool isrow0 = (rb == 0) && (w == 0) && (quad == 0);
    if (rb == 0 && w == 0) {
        const int e = lane;
        const size_t base = bhoff + e;
#define LDIN(p, i) (ISBF ? bf2f(((const u16*)(p))[i]) : ((const float*)(p))[i])
        float qe = LDIN(qv, base);
        float s[9];
#pragma unroll
        for (int j = 0; j < 9; ++j) {
            float prod = qe * LDIN(kv, base + (size_t)j * HE);
#pragma unroll
            for (int o = 1; o < 64; o <<= 1) prod += __shfl_xor(prod, o);
            s[j] = prod * 0.125f;
        }
        float mx = s[0];
#pragma unroll
        for (int j = 1; j < 9; ++j) mx = fmaxf(mx, s[j]);
        float we[9];
#pragma unroll
        for (int j = 0; j < 9; ++j) we[j] = expf(s[j] - mx);
        float denom = 9.f * we[0];
        float acc   = 9.f * we[0] * LDIN(vv, base);
#pragma unroll
        for (int j = 1; j < 9; ++j) {
            denom += we[j];
            acc   += we[j] * LDIN(vv, base + (size_t)j * HE);
        }
        float loc = acc / denom;

        float a;
        if (ISBF) {
            a = bf2f(((const u16*)alphav)[0]);
            if (!(a >= 0.0f && a <= 1.0f)) {
                float af = ((const float*)alphav)[0];
                if (af >= 0.0f && af <= 1.0f) a = af;
            }
        } else {
            a = ((const float*)alphav)[0];
            if (!(a >= 0.0f && a <= 1.0f)) {
                float ab = bf2f(((const u16*)alphav)[0]);
                if (ab >= 0.0f && ab <= 1.0f) a = ab;
            }
        }
        wgt = 1.f / (1.f + expf(-a));
#pragma unroll
        for (int et = 0; et < 4; ++et) locv[et] = __shfl(loc, et * 16 + m);
#undef LDIN
    }

    // ---- lower waves: merge partner partials, normalize, blend, store ----
    if (w < 4) {
        const float* ob = (const float*)PldsAll + (size_t)w * 2048;
        const float* sb = Scmb + w * 512;
#pragma unroll
        for (int mt = 0; mt < 2; ++mt) {
#pragma unroll
            for (int r = 0; r < 4; ++r)
                Ssum[mt][r] += sb[(mt * 4 + r) * 64 + lane];
#pragma unroll
            for (int et = 0; et < 4; ++et)
#pragma unroll
                for (int r = 0; r < 4; ++r)
                    O[mt][et][r] += ob[(mt * 16 + et * 4 + r) * 64 + lane];
        }
#pragma unroll
        for (int mt = 0; mt < 2; ++mt) {
#pragma unroll
            for (int r = 0; r < 4; ++r) {
                float inv = 1.0f / Ssum[mt][r];
                int row = row0 + g * 32 + mt * 16 + quad * 4 + r;
                size_t oo = (size_t)(b * Lv + row) * HE + h * Ev + m;
                bool blend = isrow0 && (mt == 0) && (r == 0);
#pragma unroll
                for (int et = 0; et < 4; ++et) {
                    float res = O[mt][et][r] * inv;
                    if (blend) res = wgt * res + (1.f - wgt) * locv[et];
                    if (ISBF) ((u16*)outv)[oo + et * 16] = f2bf(res);
                    else      ((float*)outv)[oo + et * 16] = res;
                }
            }
        }
    }
}

__global__ __launch_bounds__(512, 4) void attn_kernel(
    const void* __restrict__ qv, const void* __restrict__ kv,
    const void* __restrict__ vv, const void* __restrict__ alphav,
    void* __restrict__ outv)
{
    __shared__ u16 Klds[2 * 4096];      // dbuf K [key][e]; Ssum combine overlay
    __shared__ u16 Vt[2 * 4096];        // dbuf V^T [e][key], swizzled
    __shared__ u16 Plds[8 * 2048];      // per-wave P / O-combine overlay

    const int isbf = detect_isbf16((const u32*)qv, threadIdx.x & 63);
    if (isbf) attn_impl<1>(qv, kv, vv, alphav, outv, Klds, Vt, Plds);
    else      attn_impl<0>(qv, kv, vv, alphav, outv, Klds, Vt, Plds);
}

extern "C" void kernel_launch(void* const* d_in, const int* in_sizes, int n_in,
                              void* d_out, int out_size, void* d_ws, size_t ws_size,
                              hipStream_t stream) {
    hipLaunchKernelGGL(attn_kernel, dim3(512), dim3(512), 0, stream,
                       d_in[0], d_in[1], d_in[2], d_in[3], d_out);
}